// Round 8
// baseline (9174.217 us; speedup 1.0000x reference)
//
#include <hip/hip_runtime.h>
#include <hip/hip_bf16.h>
#include <math.h>

#define NN 10000
#define NE 320000

typedef __attribute__((ext_vector_type(8))) short s8v;   // 8 bf16 (4 VGPRs)
typedef __attribute__((ext_vector_type(4))) float f4v;   // MFMA accumulator

__device__ __forceinline__ short f2bf(float f) {
  unsigned u = __float_as_uint(f);
  u = u + 0x7fffu + ((u >> 16) & 1u);   // RNE
  return (short)(u >> 16);
}
__device__ __forceinline__ float bf2f(short u) {
  return __uint_as_float(((unsigned)(unsigned short)u) << 16);
}
// relu(bf16a + bf16b) for a packed pair, RNE pack (exact: fp32 add of two bf16s)
__device__ __forceinline__ unsigned cvt_pair(unsigned wa, unsigned wb) {
  float a0 = __uint_as_float(wa << 16);
  float a1 = __uint_as_float(wa & 0xFFFF0000u);
  float b0 = __uint_as_float(wb << 16);
  float b1 = __uint_as_float(wb & 0xFFFF0000u);
  float s0 = fmaxf(a0 + b0, 0.f);
  float s1 = fmaxf(a1 + b1, 0.f);
  __hip_bfloat162 h = __float22bfloat162_rn(float2{s0, s1});
  unsigned u; __builtin_memcpy(&u, &h, 4);
  return u;
}

// ================= edge sort by dst (counting sort) =================
__global__ void hist_kernel(const int* __restrict__ ei, int* __restrict__ cnt) {
  int e = blockIdx.x * 256 + threadIdx.x;
  if (e < NE) atomicAdd(&cnt[ei[NE + e]], 1);
}

__global__ void __launch_bounds__(1024)
scan_kernel(const int* __restrict__ cnt, int* __restrict__ cur) {
  __shared__ int part[1024];
  const int t = threadIdx.x;
  const int base = t * 10;
  int local[10];
  int s = 0;
#pragma unroll
  for (int u = 0; u < 10; ++u) {
    int c = (base + u < NN) ? cnt[base + u] : 0;
    local[u] = s; s += c;
  }
  part[t] = s;
  __syncthreads();
  for (int off = 1; off < 1024; off <<= 1) {
    int v = part[t];
    int w = (t >= off) ? part[t - off] : 0;
    __syncthreads();
    part[t] = v + w;
    __syncthreads();
  }
  int excl = (t == 0) ? 0 : part[t - 1];
#pragma unroll
  for (int u = 0; u < 10; ++u)
    if (base + u < NN) cur[base + u] = excl + local[u];
}

__global__ void scatter_kernel(const int* __restrict__ ei, int* __restrict__ cur,
                               int* __restrict__ sSrc, int* __restrict__ sDst) {
  int e = blockIdx.x * 256 + threadIdx.x;
  if (e < NE) {
    int d = ei[NE + e];
    int p = atomicAdd(&cur[d], 1);
    sSrc[p] = ei[e];
    sDst[p] = d;
  }
}

// ================= prep: combined/transposed weights, fp32 -> bf16 =================
// Wp1T [1024][128], Wp2T [512][256] : node-GEMM layouts (row n, col k)
// BTf1 / BTf2 : edge-GEMM fragment layout: idx = (k>>5)*(NT*32) + n*32 + (k&31)
__global__ void prep_weights(const float* __restrict__ W1a, const float* __restrict__ W1b,
                             const float* __restrict__ W2a, const float* __restrict__ W2b,
                             short* __restrict__ Wp1T, short* __restrict__ Wp2T,
                             short* __restrict__ BTf1, short* __restrict__ BTf2) {
  int i = blockIdx.x * 256 + threadIdx.x;
  if (i < 131072) {                        // Wp1T[j][k], j<1024, k<128
    int j = i >> 7, k = i & 127;
    float v;
    if (j < 512) v = W1a[k * 512 + j] - W1a[(k + 128) * 512 + j];
    else         v = W1a[(k + 128) * 512 + (j - 512)];
    Wp1T[i] = f2bf(v);
  } else if (i < 262144) {                 // Wp2T[j][k], j<512, k<256
    int t = i - 131072;
    int j = t >> 8, k = t & 255;
    float v;
    if (j < 256) v = W1b[k * 256 + j] - W1b[(k + 256) * 256 + j];
    else         v = W1b[(k + 256) * 256 + (j - 256)];
    Wp2T[t] = f2bf(v);
  } else if (i < 393216) {                 // BTf1: W2a^T in fragment layout (NT=256, K=512)
    int t = i - 262144;
    int n = t >> 9, k = t & 511;
    BTf1[(k >> 5) * 8192 + n * 32 + (k & 31)] = f2bf(W2a[k * 256 + n]);
  } else if (i < 425984) {                 // BTf2: W2b^T in fragment layout (NT=128, K=256)
    int t = i - 393216;
    int n = t >> 8, k = t & 255;
    BTf2[(k >> 5) * 4096 + n * 32 + (k & 31)] = f2bf(W2b[k * 128 + n]);
  }
}

// ================= node GEMM: C[NN][Ntot](bf16) = A[NN][K](fp32) @ BT^T + bias =================
template<int K>
__global__ void __launch_bounds__(256)
node_gemm(const float* __restrict__ A, const short* __restrict__ BT,
          const float* __restrict__ bias, int biasLen,
          short* __restrict__ C, int Ntot) {
  const int rowBase = blockIdx.x * 64;
  const int wave = threadIdx.x >> 6, lane = threadIdx.x & 63;
  const int colBase = blockIdx.y * 256 + wave * 64;
  const int lm = lane & 15, q = lane >> 4;
  f4v acc[4][4] = {};
  int arow[4];
#pragma unroll
  for (int mt = 0; mt < 4; ++mt) {
    int r = rowBase + mt * 16 + lm;
    arow[mt] = r < NN ? r : NN - 1;        // clamp; stores guarded below
  }
  for (int kk = 0; kk < K; kk += 32) {
    const int k = kk + q * 8;
    s8v aF[4], bF[4];
#pragma unroll
    for (int mt = 0; mt < 4; ++mt) {
      const float4* ap = (const float4*)(A + (size_t)arow[mt] * K + k);
      float4 x0 = ap[0], x1 = ap[1];
      s8v t;
      t[0] = f2bf(x0.x); t[1] = f2bf(x0.y); t[2] = f2bf(x0.z); t[3] = f2bf(x0.w);
      t[4] = f2bf(x1.x); t[5] = f2bf(x1.y); t[6] = f2bf(x1.z); t[7] = f2bf(x1.w);
      aF[mt] = t;
    }
#pragma unroll
    for (int nt = 0; nt < 4; ++nt)
      bF[nt] = *(const s8v*)(BT + (size_t)(colBase + nt * 16 + lm) * K + k);
#pragma unroll
    for (int mt = 0; mt < 4; ++mt)
#pragma unroll
      for (int nt = 0; nt < 4; ++nt)
        acc[mt][nt] = __builtin_amdgcn_mfma_f32_16x16x32_bf16(aF[mt], bF[nt], acc[mt][nt], 0, 0, 0);
  }
#pragma unroll
  for (int nt = 0; nt < 4; ++nt) {
    int col = colBase + nt * 16 + lm;
    float bv = (col < biasLen) ? bias[col] : 0.0f;
#pragma unroll
    for (int mt = 0; mt < 4; ++mt) {
#pragma unroll
      for (int i = 0; i < 4; ++i) {
        int row = rowBase + mt * 16 + q * 4 + i;   // C/D: col=lane&15, row=q*4+reg
        if (row < NN) C[(size_t)row * Ntot + col] = f2bf(acc[mt][nt][i] + bv);
      }
    }
  }
}

// ================= edge GEMM: LDS-free, barrier-free streaming =================
// 64 sorted edges x NT cols per 256-thr block; wave w owns cols [w*64, w*64+64).
// A-fragments gathered global->register (lane lm=row, q=k-quad), converted in-register
// (relu(A[dst]+B[src]) -> bf16); B-fragments from fragment-contiguous BTf.
// 1-kstep software pipeline: convert cur -> issue next gathers -> issue next bF -> MFMA.
// Epilogue: in-register segmented max over sorted rows + atomicMax.
template<int K, int NT>
__global__ void __launch_bounds__(256, 3)
edge_gemm_stream(const short* __restrict__ AB, const short* __restrict__ BTf,
                 const float* __restrict__ bias,
                 const int* __restrict__ sSrc, const int* __restrict__ sDst,
                 int* __restrict__ y) {
  constexpr int NW = NT / 4;         // cols per wave
  constexpr int NTL = NW / 16;       // 16-col tiles per wave
  constexpr int KSTEPS = K / 32;
  const int tid = threadIdx.x;
  const int eBase = blockIdx.x * 64;
  const int wave = tid >> 6, lane = tid & 63, lm = lane & 15, q = lane >> 4;
  const int cBase = wave * NW;

  // gather bases for rows mt*16+lm (element offsets into AB), k-chunk q*8
  const short* aP[4];
  const short* bP[4];
#pragma unroll
  for (int mt = 0; mt < 4; ++mt) {
    int rD = sDst[eBase + mt * 16 + lm];
    int rS = sSrc[eBase + mt * 16 + lm];
    aP[mt] = AB + (size_t)rD * (2 * K) + q * 8;
    bP[mt] = AB + (size_t)rS * (2 * K) + K + q * 8;
  }

  f4v acc[4][NTL] = {};
  uint4 av[4], bv[4];
  s8v bF[2][NTL];

  // prologue: gathers + bF for kstep 0
#pragma unroll
  for (int mt = 0; mt < 4; ++mt) {
    av[mt] = *(const uint4*)(aP[mt]);
    bv[mt] = *(const uint4*)(bP[mt]);
  }
#pragma unroll
  for (int nt = 0; nt < NTL; ++nt)
    bF[0][nt] = *(const s8v*)(BTf + (cBase + nt * 16 + lm) * 32 + q * 8);

  for (int ks = 0; ks < KSTEPS; ++ks) {
    // 1. convert current gathers -> A-fragments (frees av/bv)
    s8v aF[4];
#pragma unroll
    for (int mt = 0; mt < 4; ++mt) {
      unsigned o0 = cvt_pair(av[mt].x, bv[mt].x);
      unsigned o1 = cvt_pair(av[mt].y, bv[mt].y);
      unsigned o2 = cvt_pair(av[mt].z, bv[mt].z);
      unsigned o3 = cvt_pair(av[mt].w, bv[mt].w);
      s8v t;
      ((unsigned*)&t)[0] = o0; ((unsigned*)&t)[1] = o1;
      ((unsigned*)&t)[2] = o2; ((unsigned*)&t)[3] = o3;
      aF[mt] = t;
    }
    // 2. issue next kstep's gathers (land during MFMA below)
    if (ks + 1 < KSTEPS) {
      const int kn = (ks + 1) * 32;
#pragma unroll
      for (int mt = 0; mt < 4; ++mt) {
        av[mt] = *(const uint4*)(aP[mt] + kn);
        bv[mt] = *(const uint4*)(bP[mt] + kn);
      }
      // 3. issue next kstep's B-fragments
#pragma unroll
      for (int nt = 0; nt < NTL; ++nt)
        bF[(ks + 1) & 1][nt] = *(const s8v*)(BTf + (size_t)(ks + 1) * (NT * 32) +
                                             (cBase + nt * 16 + lm) * 32 + q * 8);
    }
    // 4. MFMA on current fragments
#pragma unroll
    for (int mt = 0; mt < 4; ++mt)
#pragma unroll
      for (int nt = 0; nt < NTL; ++nt)
        acc[mt][nt] = __builtin_amdgcn_mfma_f32_16x16x32_bf16(aF[mt], bF[ks & 1][nt], acc[mt][nt], 0, 0, 0);
  }

  // epilogue: rows q*4+i are consecutive sorted edges -> in-register segmented max
#pragma unroll
  for (int mt = 0; mt < 4; ++mt) {
    const int gr = mt * 16 + q * 4;
    const int4 dd = *(const int4*)(sDst + eBase + gr);   // dsts of this lane's 4 rows
#pragma unroll
    for (int nt = 0; nt < NTL; ++nt) {
      int col = cBase + nt * 16 + lm;
      float bvv = bias[col];
      int curd = dd.x;
      float curv = acc[mt][nt][0] + bvv;
      float v1 = acc[mt][nt][1] + bvv;
      float v2 = acc[mt][nt][2] + bvv;
      float v3 = acc[mt][nt][3] + bvv;
      if (dd.y == curd) curv = fmaxf(curv, v1);
      else { if (curv > 0.f) atomicMax(&y[(size_t)curd * NT + col], __float_as_int(curv)); curd = dd.y; curv = v1; }
      if (dd.z == curd) curv = fmaxf(curv, v2);
      else { if (curv > 0.f) atomicMax(&y[(size_t)curd * NT + col], __float_as_int(curv)); curd = dd.z; curv = v2; }
      if (dd.w == curd) curv = fmaxf(curv, v3);
      else { if (curv > 0.f) atomicMax(&y[(size_t)curd * NT + col], __float_as_int(curv)); curd = dd.w; curv = v3; }
      if (curv > 0.f) atomicMax(&y[(size_t)curd * NT + col], __float_as_int(curv));
    }
  }
}

// ================= head: one wave per node =================
__global__ void __launch_bounds__(64)
head_kernel(const float* __restrict__ y2, const float* __restrict__ W3,
            const float* __restrict__ b3, const float* __restrict__ W4,
            const float* __restrict__ b4, float* __restrict__ out) {
  const int n = blockIdx.x, j = threadIdx.x;
  const float* yr = y2 + (size_t)n * 128;
  float acc = 0.f;
#pragma unroll
  for (int k = 0; k < 128; ++k) acc += yr[k] * W3[k * 64 + j];
  acc += b3[j];
  float h = acc > 0.f ? acc : 0.f;
  float p = h * W4[j];
#pragma unroll
  for (int off = 32; off; off >>= 1) p += __shfl_down(p, off);
  if (j == 0) {
    float z = p + b4[0];
    out[n] = 1.f / (1.f + expf(-z));
  }
}

__global__ void diag_kernel(float* out, float v) { out[0] = v; }

extern "C" void kernel_launch(void* const* d_in, const int* in_sizes, int n_in,
                              void* d_out, int out_size, void* d_ws, size_t ws_size,
                              hipStream_t stream) {
  const float* x   = (const float*)d_in[0];
  const int*   ei  = (const int*)d_in[1];
  const float* W1a = (const float*)d_in[2];
  const float* b1a = (const float*)d_in[3];
  const float* W2a = (const float*)d_in[4];
  const float* b2a = (const float*)d_in[5];
  const float* W1b = (const float*)d_in[6];
  const float* b1b = (const float*)d_in[7];
  const float* W2b = (const float*)d_in[8];
  const float* b2b = (const float*)d_in[9];
  const float* W3  = (const float*)d_in[10];
  const float* b3  = (const float*)d_in[11];
  const float* W4  = (const float*)d_in[12];
  const float* b4  = (const float*)d_in[13];

  // workspace layout (peak 34,211,968 B)
  char* ws = (char*)d_ws;
  short* Wp1T = (short*)(ws + 0);          //  262144 B [1024][128]
  short* Wp2T = (short*)(ws + 262144);     //  262144 B [512][256]
  short* BTf1 = (short*)(ws + 524288);     //  262144 B W2a^T fragment layout
  short* BTf2 = (short*)(ws + 786432);     //   65536 B W2b^T fragment layout
  short* A1B1 = (short*)(ws + 851968);     // 20480000 B [10000][1024] bf16
  short* A2B2 = (short*)(ws + 851968);     // reuse (A1B1 dead): [10000][512]
  int*   Y1   = (int*)(ws + 21331968);     // 10240000 B [10000][256] fp32
  int*   Y2   = (int*)(ws + 21331968);     // reuse (Y1 dead): [10000][128] fp32
  int*   cnt  = (int*)(ws + 31571968);     //    40000 B
  int*   cur  = (int*)(ws + 31611968);     //    40000 B
  int*   sSrc = (int*)(ws + 31651968);     //  1280000 B
  int*   sDst = (int*)(ws + 32931968);     //  1280000 B

  if (ws_size < 34211968) {                // diagnostic: encode ws_size in the absmax error
    diag_kernel<<<1, 1, 0, stream>>>((float*)d_out, (float)ws_size);
    return;
  }

  // ---- counting sort by dst ----
  hipMemsetAsync(cnt, 0, 40000, stream);
  hist_kernel<<<1250, 256, 0, stream>>>(ei, cnt);
  scan_kernel<<<1, 1024, 0, stream>>>(cnt, cur);
  scatter_kernel<<<1250, 256, 0, stream>>>(ei, cur, sSrc, sDst);

  prep_weights<<<1664, 256, 0, stream>>>(W1a, W1b, W2a, W2b, Wp1T, Wp2T, BTf1, BTf2);

  // EdgeConv 1
  node_gemm<128><<<dim3(157, 4), 256, 0, stream>>>(x, Wp1T, b1a, 512, A1B1, 1024);
  hipMemsetAsync(Y1, 0, (size_t)NN * 256 * 4, stream);
  edge_gemm_stream<512, 256><<<5000, 256, 0, stream>>>(A1B1, BTf1, b2a, sSrc, sDst, Y1);

  // EdgeConv 2 (A2B2 overwrites dead A1B1; Y2 memset AFTER node_gemm reads aliased Y1)
  node_gemm<256><<<dim3(157, 2), 256, 0, stream>>>((const float*)Y1, Wp2T, b1b, 256, A2B2, 512);
  hipMemsetAsync(Y2, 0, (size_t)NN * 128 * 4, stream);
  edge_gemm_stream<256, 128><<<5000, 256, 0, stream>>>(A2B2, BTf2, b2b, sSrc, sDst, Y2);

  // Head
  head_kernel<<<NN, 64, 0, stream>>>((const float*)Y2, W3, b3, W4, b4, (float*)d_out);
}

// Round 9
// 511.087 us; speedup vs baseline: 17.9504x; 17.9504x over previous
//
#include <hip/hip_runtime.h>
#include <hip/hip_bf16.h>
#include <math.h>

#define NN 10000
#define NE 320000

typedef __attribute__((ext_vector_type(8))) short s8v;   // 8 bf16 (4 VGPRs)
typedef __attribute__((ext_vector_type(4))) float f4v;   // MFMA accumulator

__device__ __forceinline__ short f2bf(float f) {
  unsigned u = __float_as_uint(f);
  u = u + 0x7fffu + ((u >> 16) & 1u);   // RNE
  return (short)(u >> 16);
}
__device__ __forceinline__ float bf2f(short u) {
  return __uint_as_float(((unsigned)(unsigned short)u) << 16);
}
// relu(bf16a + bf16b) for a packed pair, RNE pack (exact: fp32 add of two bf16s)
__device__ __forceinline__ unsigned cvt_pair(unsigned wa, unsigned wb) {
  float a0 = __uint_as_float(wa << 16);
  float a1 = __uint_as_float(wa & 0xFFFF0000u);
  float b0 = __uint_as_float(wb << 16);
  float b1 = __uint_as_float(wb & 0xFFFF0000u);
  float s0 = fmaxf(a0 + b0, 0.f);
  float s1 = fmaxf(a1 + b1, 0.f);
  __hip_bfloat162 h = __float22bfloat162_rn(float2{s0, s1});
  unsigned u; __builtin_memcpy(&u, &h, 4);
  return u;
}

// ================= edge sort by dst (counting sort) =================
__global__ void hist_kernel(const int* __restrict__ ei, int* __restrict__ cnt) {
  int e = blockIdx.x * 256 + threadIdx.x;
  if (e < NE) atomicAdd(&cnt[ei[NE + e]], 1);
}

__global__ void __launch_bounds__(1024)
scan_kernel(const int* __restrict__ cnt, int* __restrict__ cur) {
  __shared__ int part[1024];
  const int t = threadIdx.x;
  const int base = t * 10;
  int local[10];
  int s = 0;
#pragma unroll
  for (int u = 0; u < 10; ++u) {
    int c = (base + u < NN) ? cnt[base + u] : 0;
    local[u] = s; s += c;
  }
  part[t] = s;
  __syncthreads();
  for (int off = 1; off < 1024; off <<= 1) {
    int v = part[t];
    int w = (t >= off) ? part[t - off] : 0;
    __syncthreads();
    part[t] = v + w;
    __syncthreads();
  }
  int excl = (t == 0) ? 0 : part[t - 1];
#pragma unroll
  for (int u = 0; u < 10; ++u)
    if (base + u < NN) cur[base + u] = excl + local[u];
}

__global__ void scatter_kernel(const int* __restrict__ ei, int* __restrict__ cur,
                               int* __restrict__ sSrc, int* __restrict__ sDst) {
  int e = blockIdx.x * 256 + threadIdx.x;
  if (e < NE) {
    int d = ei[NE + e];
    int p = atomicAdd(&cur[d], 1);
    sSrc[p] = ei[e];
    sDst[p] = d;
  }
}

// ================= prep: combined/transposed weights, fp32 -> bf16 =================
// Wp1T [1024][128], Wp2T [512][256] : node-GEMM layouts (row n, col k)
// BTf1 / BTf2 : edge-GEMM fragment layout: idx = (k>>5)*(NT*32) + n*32 + (k&31)
__global__ void prep_weights(const float* __restrict__ W1a, const float* __restrict__ W1b,
                             const float* __restrict__ W2a, const float* __restrict__ W2b,
                             short* __restrict__ Wp1T, short* __restrict__ Wp2T,
                             short* __restrict__ BTf1, short* __restrict__ BTf2) {
  int i = blockIdx.x * 256 + threadIdx.x;
  if (i < 131072) {                        // Wp1T[j][k], j<1024, k<128
    int j = i >> 7, k = i & 127;
    float v;
    if (j < 512) v = W1a[k * 512 + j] - W1a[(k + 128) * 512 + j];
    else         v = W1a[(k + 128) * 512 + (j - 512)];
    Wp1T[i] = f2bf(v);
  } else if (i < 262144) {                 // Wp2T[j][k], j<512, k<256
    int t = i - 131072;
    int j = t >> 8, k = t & 255;
    float v;
    if (j < 256) v = W1b[k * 256 + j] - W1b[(k + 256) * 256 + j];
    else         v = W1b[(k + 256) * 256 + (j - 256)];
    Wp2T[t] = f2bf(v);
  } else if (i < 393216) {                 // BTf1: W2a^T fragment layout (NT=256, K=512)
    int t = i - 262144;
    int n = t >> 9, k = t & 511;
    BTf1[(k >> 5) * 8192 + n * 32 + (k & 31)] = f2bf(W2a[k * 256 + n]);
  } else if (i < 425984) {                 // BTf2: W2b^T fragment layout (NT=128, K=256)
    int t = i - 393216;
    int n = t >> 8, k = t & 255;
    BTf2[(k >> 5) * 4096 + n * 32 + (k & 31)] = f2bf(W2b[k * 128 + n]);
  }
}

// ================= node GEMM: C[NN][Ntot](bf16) = A[NN][K](fp32) @ BT^T + bias =================
template<int K>
__global__ void __launch_bounds__(256)
node_gemm(const float* __restrict__ A, const short* __restrict__ BT,
          const float* __restrict__ bias, int biasLen,
          short* __restrict__ C, int Ntot) {
  const int rowBase = blockIdx.x * 64;
  const int wave = threadIdx.x >> 6, lane = threadIdx.x & 63;
  const int colBase = blockIdx.y * 256 + wave * 64;
  const int lm = lane & 15, q = lane >> 4;
  f4v acc[4][4] = {};
  int arow[4];
#pragma unroll
  for (int mt = 0; mt < 4; ++mt) {
    int r = rowBase + mt * 16 + lm;
    arow[mt] = r < NN ? r : NN - 1;        // clamp; stores guarded below
  }
  for (int kk = 0; kk < K; kk += 32) {
    const int k = kk + q * 8;
    s8v aF[4], bF[4];
#pragma unroll
    for (int mt = 0; mt < 4; ++mt) {
      const float4* ap = (const float4*)(A + (size_t)arow[mt] * K + k);
      float4 x0 = ap[0], x1 = ap[1];
      s8v t;
      t[0] = f2bf(x0.x); t[1] = f2bf(x0.y); t[2] = f2bf(x0.z); t[3] = f2bf(x0.w);
      t[4] = f2bf(x1.x); t[5] = f2bf(x1.y); t[6] = f2bf(x1.z); t[7] = f2bf(x1.w);
      aF[mt] = t;
    }
#pragma unroll
    for (int nt = 0; nt < 4; ++nt)
      bF[nt] = *(const s8v*)(BT + (size_t)(colBase + nt * 16 + lm) * K + k);
#pragma unroll
    for (int mt = 0; mt < 4; ++mt)
#pragma unroll
      for (int nt = 0; nt < 4; ++nt)
        acc[mt][nt] = __builtin_amdgcn_mfma_f32_16x16x32_bf16(aF[mt], bF[nt], acc[mt][nt], 0, 0, 0);
  }
#pragma unroll
  for (int nt = 0; nt < 4; ++nt) {
    int col = colBase + nt * 16 + lm;
    float bv = (col < biasLen) ? bias[col] : 0.0f;
#pragma unroll
    for (int mt = 0; mt < 4; ++mt) {
#pragma unroll
      for (int i = 0; i < 4; ++i) {
        int row = rowBase + mt * 16 + q * 4 + i;   // C/D: col=lane&15, row=q*4+reg
        if (row < NN) C[(size_t)row * Ntot + col] = f2bf(acc[mt][nt][i] + bv);
      }
    }
  }
}

// ================= edge GEMM: R6 structure + register prefetch of gathers =================
// 64 sorted edges x NT cols per 256-thr block; wave w owns cols [w*64, w*64+64).
// Per k-tile: issue bF loads (fly during convert+barrier) -> convert PREFETCHED
// gather regs -> LDS (dbuf) -> prefetch next tile's gathers (fly during MFMA) ->
// barrier -> MFMA (aF from LDS, bF from regs). No global wait in the serial chain.
// Epilogue: in-register segmented max over sorted rows + atomicMax.
template<int K, int NT>
__global__ void __launch_bounds__(256, 3)
edge_gemm_pf(const short* __restrict__ AB, const short* __restrict__ BTf,
             const float* __restrict__ bias,
             const int* __restrict__ sSrc, const int* __restrict__ sDst,
             int* __restrict__ y) {
  constexpr int KT = 64;            // k-tile
  constexpr int KTP = 72;           // LDS pitch (shorts): breaks bank alignment, keeps 16B
  constexpr int TILES = K / KT;
  constexpr int NW = NT / 4;        // cols per wave
  constexpr int NTL = NW / 16;
  __shared__ __align__(16) short hA[2][64 * KTP];   // 2 x 9216 B
  __shared__ int srcS[64], dstS[64];

  const int tid = threadIdx.x;
  const int eBase = blockIdx.x * 64;
  const int wave = tid >> 6, lane = tid & 63, lm = lane & 15, q = lane >> 4;
  const int cBase = wave * NW;

  if (tid < 64) { srcS[tid] = sSrc[eBase + tid]; dstS[tid] = sDst[eBase + tid]; }
  __syncthreads();

  // per-thread staging coords: 2 chunks (rows r0 and r0+32), fixed column chunk kc0
  const int r0 = tid >> 3, kc0 = (tid & 7) * 8;
  const int r1 = r0 + 32;
  const size_t dO0 = (size_t)dstS[r0] * (2 * K) + kc0;
  const size_t sO0 = (size_t)srcS[r0] * (2 * K) + K + kc0;
  const size_t dO1 = (size_t)dstS[r1] * (2 * K) + kc0;
  const size_t sO1 = (size_t)srcS[r1] * (2 * K) + K + kc0;

  f4v acc[4][NTL] = {};

  // prologue: prefetch tile 0's gathers
  uint4 av0 = *(const uint4*)(AB + dO0);
  uint4 bv0 = *(const uint4*)(AB + sO0);
  uint4 av1 = *(const uint4*)(AB + dO1);
  uint4 bv1 = *(const uint4*)(AB + sO1);

  for (int t = 0; t < TILES; ++t) {
    // 1. issue bF loads for this tile (dense 1KB wave-requests; fly during convert+barrier)
    s8v bF[2][NTL];
#pragma unroll
    for (int s = 0; s < 2; ++s)
#pragma unroll
      for (int nt = 0; nt < NTL; ++nt)
        bF[s][nt] = *(const s8v*)(BTf + (size_t)(t * 2 + s) * (NT * 32) +
                                  (cBase + nt * 16 + lm) * 32 + q * 8);
    // 2. convert prefetched gathers -> LDS (double-buffered)
    short* hbuf = hA[t & 1];
    {
      uint4 o;
      o.x = cvt_pair(av0.x, bv0.x); o.y = cvt_pair(av0.y, bv0.y);
      o.z = cvt_pair(av0.z, bv0.z); o.w = cvt_pair(av0.w, bv0.w);
      *(uint4*)(&hbuf[r0 * KTP + kc0]) = o;
      uint4 o1;
      o1.x = cvt_pair(av1.x, bv1.x); o1.y = cvt_pair(av1.y, bv1.y);
      o1.z = cvt_pair(av1.z, bv1.z); o1.w = cvt_pair(av1.w, bv1.w);
      *(uint4*)(&hbuf[r1 * KTP + kc0]) = o1;
    }
    // 3. prefetch next tile's gathers (land during barrier + MFMA below)
    if (t + 1 < TILES) {
      const int kn = (t + 1) * KT;
      av0 = *(const uint4*)(AB + dO0 + kn);
      bv0 = *(const uint4*)(AB + sO0 + kn);
      av1 = *(const uint4*)(AB + dO1 + kn);
      bv1 = *(const uint4*)(AB + sO1 + kn);
    }
    __syncthreads();   // ds_writes visible; prefetches remain in flight
    // 4. MFMA: aF from LDS, bF from registers
#pragma unroll
    for (int s = 0; s < 2; ++s) {
      const int kl = s * 32 + q * 8;
      s8v aF[4];
#pragma unroll
      for (int mt = 0; mt < 4; ++mt)
        aF[mt] = *(const s8v*)(&hbuf[(mt * 16 + lm) * KTP + kl]);
#pragma unroll
      for (int mt = 0; mt < 4; ++mt)
#pragma unroll
        for (int nt = 0; nt < NTL; ++nt)
          acc[mt][nt] = __builtin_amdgcn_mfma_f32_16x16x32_bf16(aF[mt], bF[s][nt], acc[mt][nt], 0, 0, 0);
    }
  }

  // epilogue: rows q*4+i are consecutive sorted edges -> in-register segmented max
#pragma unroll
  for (int nt = 0; nt < NTL; ++nt) {
    int col = cBase + nt * 16 + lm;
    float bvv = bias[col];
#pragma unroll
    for (int mt = 0; mt < 4; ++mt) {
      const int gr = mt * 16 + q * 4;
      int curd = dstS[gr];
      float curv = acc[mt][nt][0] + bvv;
#pragma unroll
      for (int i = 1; i < 4; ++i) {
        int d = dstS[gr + i];
        float v = acc[mt][nt][i] + bvv;
        if (d == curd) {
          curv = fmaxf(curv, v);
        } else {
          if (curv > 0.f) atomicMax(&y[(size_t)curd * NT + col], __float_as_int(curv));
          curd = d; curv = v;
        }
      }
      if (curv > 0.f) atomicMax(&y[(size_t)curd * NT + col], __float_as_int(curv));
    }
  }
}

// ================= head: one wave per node =================
__global__ void __launch_bounds__(64)
head_kernel(const float* __restrict__ y2, const float* __restrict__ W3,
            const float* __restrict__ b3, const float* __restrict__ W4,
            const float* __restrict__ b4, float* __restrict__ out) {
  const int n = blockIdx.x, j = threadIdx.x;
  const float* yr = y2 + (size_t)n * 128;
  float acc = 0.f;
#pragma unroll
  for (int k = 0; k < 128; ++k) acc += yr[k] * W3[k * 64 + j];
  acc += b3[j];
  float h = acc > 0.f ? acc : 0.f;
  float p = h * W4[j];
#pragma unroll
  for (int off = 32; off; off >>= 1) p += __shfl_down(p, off);
  if (j == 0) {
    float z = p + b4[0];
    out[n] = 1.f / (1.f + expf(-z));
  }
}

__global__ void diag_kernel(float* out, float v) { out[0] = v; }

extern "C" void kernel_launch(void* const* d_in, const int* in_sizes, int n_in,
                              void* d_out, int out_size, void* d_ws, size_t ws_size,
                              hipStream_t stream) {
  const float* x   = (const float*)d_in[0];
  const int*   ei  = (const int*)d_in[1];
  const float* W1a = (const float*)d_in[2];
  const float* b1a = (const float*)d_in[3];
  const float* W2a = (const float*)d_in[4];
  const float* b2a = (const float*)d_in[5];
  const float* W1b = (const float*)d_in[6];
  const float* b1b = (const float*)d_in[7];
  const float* W2b = (const float*)d_in[8];
  const float* b2b = (const float*)d_in[9];
  const float* W3  = (const float*)d_in[10];
  const float* b3  = (const float*)d_in[11];
  const float* W4  = (const float*)d_in[12];
  const float* b4  = (const float*)d_in[13];

  // workspace layout (peak 34,211,968 B)
  char* ws = (char*)d_ws;
  short* Wp1T = (short*)(ws + 0);          //  262144 B [1024][128]
  short* Wp2T = (short*)(ws + 262144);     //  262144 B [512][256]
  short* BTf1 = (short*)(ws + 524288);     //  262144 B W2a^T fragment layout
  short* BTf2 = (short*)(ws + 786432);     //   65536 B W2b^T fragment layout
  short* A1B1 = (short*)(ws + 851968);     // 20480000 B [10000][1024] bf16
  short* A2B2 = (short*)(ws + 851968);     // reuse (A1B1 dead): [10000][512]
  int*   Y1   = (int*)(ws + 21331968);     // 10240000 B [10000][256] fp32
  int*   Y2   = (int*)(ws + 21331968);     // reuse (Y1 dead): [10000][128] fp32
  int*   cnt  = (int*)(ws + 31571968);     //    40000 B
  int*   cur  = (int*)(ws + 31611968);     //    40000 B
  int*   sSrc = (int*)(ws + 31651968);     //  1280000 B
  int*   sDst = (int*)(ws + 32931968);     //  1280000 B

  if (ws_size < 34211968) {                // diagnostic: encode ws_size in the absmax error
    diag_kernel<<<1, 1, 0, stream>>>((float*)d_out, (float)ws_size);
    return;
  }

  // ---- counting sort by dst ----
  hipMemsetAsync(cnt, 0, 40000, stream);
  hist_kernel<<<1250, 256, 0, stream>>>(ei, cnt);
  scan_kernel<<<1, 1024, 0, stream>>>(cnt, cur);
  scatter_kernel<<<1250, 256, 0, stream>>>(ei, cur, sSrc, sDst);

  prep_weights<<<1664, 256, 0, stream>>>(W1a, W1b, W2a, W2b, Wp1T, Wp2T, BTf1, BTf2);

  // EdgeConv 1
  node_gemm<128><<<dim3(157, 4), 256, 0, stream>>>(x, Wp1T, b1a, 512, A1B1, 1024);
  hipMemsetAsync(Y1, 0, (size_t)NN * 256 * 4, stream);
  edge_gemm_pf<512, 256><<<5000, 256, 0, stream>>>(A1B1, BTf1, b2a, sSrc, sDst, Y1);

  // EdgeConv 2 (A2B2 overwrites dead A1B1; Y2 memset AFTER node_gemm reads aliased Y1)
  node_gemm<256><<<dim3(157, 2), 256, 0, stream>>>((const float*)Y1, Wp2T, b1b, 256, A2B2, 512);
  hipMemsetAsync(Y2, 0, (size_t)NN * 128 * 4, stream);
  edge_gemm_pf<256, 128><<<5000, 256, 0, stream>>>(A2B2, BTf2, b2b, sSrc, sDst, Y2);

  // Head
  head_kernel<<<NN, 64, 0, stream>>>((const float*)Y2, W3, b3, W4, b4, (float*)d_out);
}